// Round 7
// baseline (36.472 us; speedup 1.0000x reference)
//
#include <hip/hip_runtime.h>
#include <math.h>

#define INFBITS 0x7F800000u
#define TCH 32           // target points staged per chamfer block
#define PTS 16           // query points per thread (1 LDS b128 feeds 48 VALU)
#define DICE_BLOCKS 512

// ---------- block-wide sum (blockDim.x == 256, 4 waves) ----------
__device__ __forceinline__ float block_sum256(float v) {
#pragma unroll
    for (int o = 32; o > 0; o >>= 1) v += __shfl_down(v, o, 64);
    __shared__ float sb[4];
    if ((threadIdx.x & 63) == 0) sb[threadIdx.x >> 6] = v;
    __syncthreads();
    float r = sb[0] + sb[1] + sb[2] + sb[3];
    __syncthreads();
    return r;
}

// ---------- K1: fused dice partials + chamfer partial mins ----------
// blocks [0, DICE_BLOCKS)          : dice grid-stride partial sums
// blocks [DICE_BLOCKS, +2*gxp*chm) : chamfer partial mins
//
// Budget (R4-R6 lessons): VGPR <= ~72 (>=4 waves/SIMD, no spills); the LDS
// pipe is ONE unit per CU shared by 4 SIMDs, and a broadcast ds_read_b128
// still costs ~12 cyc — at PTS=8 LDS demand equals VALU demand (5.1 us each),
// so PTS=16 halves LDS demand per unit work -> chamfer is purely VALU-bound.
// ||a||^2 stays deferred to K2 (min is invariant to per-point constants).
__global__ void __launch_bounds__(256) fused_partials(
        const float4* __restrict__ p4, const float4* __restrict__ t4, int n4,
        float* __restrict__ inter_p, float* __restrict__ uni_p,
        const float2* __restrict__ P, const float2* __restrict__ T,
        int N, int M, float* __restrict__ pm, int npm, int chm, int gxp,
        unsigned int* __restrict__ counter) {
    int bid = blockIdx.x;
    if (bid == 0 && threadIdx.x == 0) *counter = 0u;   // reset K2's semaphore

    if (bid < DICE_BLOCKS) {
        float inter = 0.f, uni = 0.f;
#pragma unroll 2
        for (int i = bid * 256 + threadIdx.x; i < n4; i += DICE_BLOCKS * 256) {
            float4 p = p4[i];
            float4 t = t4[i];
            float s;
            s = __fdividef(1.f, 1.f + __expf(-p.x)); inter = fmaf(s, t.x, inter); uni += s + t.x;
            s = __fdividef(1.f, 1.f + __expf(-p.y)); inter = fmaf(s, t.y, inter); uni += s + t.y;
            s = __fdividef(1.f, 1.f + __expf(-p.z)); inter = fmaf(s, t.z, inter); uni += s + t.z;
            s = __fdividef(1.f, 1.f + __expf(-p.w)); inter = fmaf(s, t.w, inter); uni += s + t.w;
        }
        float bi = block_sum256(inter);
        float bu = block_sum256(uni);
        if (threadIdx.x == 0) { inter_p[bid] = bi; uni_p[bid] = bu; }
        return;
    }

    // ---- chamfer partials ----
    int cb      = bid - DICE_BLOCKS;
    int per_dir = gxp * chm;
    int dir     = cb / per_dir;
    int rem     = cb - dir * per_dir;
    int cy      = rem / gxp;          // target chunk
    int cx      = rem - cy * gxp;     // query-point group
    const float2* A = dir ? T : P;
    const float2* B = dir ? P : T;
    int nA = dir ? M : N;
    int nB = dir ? N : M;

    int tb = cy * TCH;
    if (tb >= nB) return;             // uniform per block

    __shared__ float4 bs[TCH];
    int t = threadIdx.x;
    if (t < TCH) {
        float bx = 0.f, by = 0.f, s2 = __uint_as_float(INFBITS);
        if (tb + t < nB) {
            float2 b = B[tb + t];
            bx = b.x; by = b.y;
            s2 = fmaf(bx, bx, by * by);
        }
        bs[t] = make_float4(bx, by, s2, 0.f);   // OOB pads +inf -> never wins min
    }
    __syncthreads();

    int abase = cx * (PTS * 256);
    float nx[PTS], ny[PTS], mn[PTS];
#pragma unroll
    for (int i = 0; i < PTS; ++i) {
        int p = abase + i * 256 + t;
        nx[i] = 0.f; ny[i] = 0.f;
        mn[i] = __uint_as_float(INFBITS);
        if (p < nA) {
            float2 a = A[p];
            nx[i] = -2.f * a.x;
            ny[i] = -2.f * a.y;
        }
    }

    // 1 broadcast ds_read_b128 per j feeds 48 VALU insts; 16 independent
    // min-chains give ILP; 4 waves/SIMD give TLP.
#pragma unroll 4
    for (int j = 0; j < TCH; ++j) {
        float4 b = bs[j];
#pragma unroll
        for (int i = 0; i < PTS; ++i)
            mn[i] = fminf(mn[i], fmaf(nx[i], b.x, fmaf(ny[i], b.y, b.z)));
    }

    float* dstc = pm + ((size_t)dir * chm + cy) * npm;
#pragma unroll
    for (int i = 0; i < PTS; ++i) {
        int p = abase + i * 256 + t;
        if (p < nA) dstc[p] = mn[i];
    }
}

// ---------- K2: fused finalize ----------
// grid = 2*gxf blocks; per-point min across chunks, + ||a||^2, block sum;
// last block combines dice partials + chamfer block sums into the scalar.
__global__ void __launch_bounds__(256) finalize_all(
        const float* __restrict__ pm, int npm, int chm,
        int N, int M, int nch0, int nch1,
        const float2* __restrict__ P, const float2* __restrict__ T,
        const float* __restrict__ inter_p, const float* __restrict__ uni_p,
        float* __restrict__ bsum, unsigned int* __restrict__ counter,
        int gxf, float* __restrict__ out) {
    int blk = blockIdx.x;
    int dir = blk / gxf;
    int bx  = blk - dir * gxf;
    int nA  = dir ? M : N;
    int nch = dir ? nch1 : nch0;
    const float2* A = dir ? T : P;

    int p = bx * 256 + threadIdx.x;
    float v = 0.f;
    if (p < nA) {
        const float* src = pm + (size_t)dir * chm * npm + p;
        float m = __uint_as_float(INFBITS);
#pragma unroll 16
        for (int c = 0; c < nch; ++c) m = fminf(m, src[(size_t)c * npm]);
        float2 a = A[p];
        v = m + fmaf(a.x, a.x, a.y * a.y);   // add the deferred ||a||^2
    }
    float s = block_sum256(v);

    __shared__ int is_last;
    if (threadIdx.x == 0) {
        bsum[blk] = s;
        __threadfence();
        unsigned int old = atomicAdd(counter, 1u);
        is_last = (old == (unsigned)(2 * gxf - 1));
    }
    __syncthreads();
    if (!is_last) return;
    __threadfence();

    float inter = 0.f, uni = 0.f, c0 = 0.f, c1 = 0.f;
    for (int i = threadIdx.x; i < DICE_BLOCKS; i += 256) {
        inter += inter_p[i];
        uni   += uni_p[i];
    }
    const volatile float* vb = bsum;
    for (int i = threadIdx.x; i < gxf; i += 256) {
        c0 += vb[i];
        c1 += vb[gxf + i];
    }
    float bi  = block_sum256(inter);
    float bu  = block_sum256(uni);
    float bc0 = block_sum256(c0);
    float bc1 = block_sum256(c1);
    if (threadIdx.x == 0) {
        const float SMOOTH = 1e-6f;
        float dice    = (2.f * bi + SMOOTH) / (bu + SMOOTH);
        float chamfer = bc0 / (float)N + bc1 / (float)M;
        out[0] = 0.5f * (1.f - dice) + 0.5f * chamfer;
    }
}

extern "C" void kernel_launch(void* const* d_in, const int* in_sizes, int n_in,
                              void* d_out, int out_size, void* d_ws, size_t ws_size,
                              hipStream_t stream) {
    const float*  pred = (const float*)d_in[0];
    const float*  targ = (const float*)d_in[1];
    const float2* pp   = (const float2*)d_in[2];
    const float2* tp   = (const float2*)d_in[3];
    int n = in_sizes[0];
    int N = in_sizes[2] / 2;
    int M = in_sizes[3] / 2;
    float* out = (float*)d_out;

    int npm  = N > M ? N : M;
    int nch0 = (M + TCH - 1) / TCH;
    int nch1 = (N + TCH - 1) / TCH;
    int chm  = nch0 > nch1 ? nch0 : nch1;
    int gxp  = (npm + PTS * 256 - 1) / (PTS * 256);
    int gxf  = (npm + 255) / 256;

    // ws layout: pm | inter_p | uni_p | bsum | counter
    char*  ws      = (char*)d_ws;
    float* pm      = (float*)ws;
    size_t pm_bytes = (size_t)2 * chm * npm * sizeof(float);
    size_t off     = (pm_bytes + 255) & ~(size_t)255;
    float* inter_p = (float*)(ws + off);
    float* uni_p   = inter_p + DICE_BLOCKS;
    float* bsum    = uni_p + DICE_BLOCKS;
    unsigned int* counter = (unsigned int*)(bsum + 2 * gxf);

    int cham_blocks = 2 * gxp * chm;
    fused_partials<<<DICE_BLOCKS + cham_blocks, 256, 0, stream>>>(
        (const float4*)pred, (const float4*)targ, n / 4,
        inter_p, uni_p, pp, tp, N, M, pm, npm, chm, gxp, counter);

    finalize_all<<<2 * gxf, 256, 0, stream>>>(pm, npm, chm, N, M, nch0, nch1,
                                              pp, tp, inter_p, uni_p, bsum,
                                              counter, gxf, out);
}

// Round 8
// 33.665 us; speedup vs baseline: 1.0834x; 1.0834x over previous
//
#include <hip/hip_runtime.h>
#include <math.h>

#define INFBITS 0x7F800000u
#define TCH 128          // target points staged per chamfer block (R6 value)
#define PTS 16           // query points per thread: 1 LDS b128 feeds 48 VALU
#define DICE_BLOCKS 512

// ---------- block-wide sum (blockDim.x == 256, 4 waves) ----------
__device__ __forceinline__ float block_sum256(float v) {
#pragma unroll
    for (int o = 32; o > 0; o >>= 1) v += __shfl_down(v, o, 64);
    __shared__ float sb[4];
    if ((threadIdx.x & 63) == 0) sb[threadIdx.x >> 6] = v;
    __syncthreads();
    float r = sb[0] + sb[1] + sb[2] + sb[3];
    __syncthreads();
    return r;
}

// ---------- K1: fused dice partials + chamfer partial mins ----------
// blocks [0, DICE_BLOCKS)          : dice grid-stride partial sums
// blocks [DICE_BLOCKS, +2*gxp*chm) : chamfer partial mins
//
// R8 change vs R6: PTS 8->16 ONLY (TCH stays 128). Theory: LDS pipe is one
// unit per CU shared by 4 SIMDs; at PTS=8 broadcast ds_read_b128 demand
// (5.1 us) equals VALU demand (5.1 us) -> coupled stall. PTS=16 halves LDS
// demand per unit work. VGPR ~96 -> 5 waves/SIMD (no cliff, no spill).
// ||a||^2 stays deferred to K2 (min is invariant to per-point constants).
__global__ void __launch_bounds__(256) fused_partials(
        const float4* __restrict__ p4, const float4* __restrict__ t4, int n4,
        float* __restrict__ inter_p, float* __restrict__ uni_p,
        const float2* __restrict__ P, const float2* __restrict__ T,
        int N, int M, float* __restrict__ pm, int npm, int chm, int gxp,
        unsigned int* __restrict__ counter) {
    int bid = blockIdx.x;
    if (bid == 0 && threadIdx.x == 0) *counter = 0u;   // reset K2's semaphore

    if (bid < DICE_BLOCKS) {
        float inter = 0.f, uni = 0.f;
#pragma unroll 2
        for (int i = bid * 256 + threadIdx.x; i < n4; i += DICE_BLOCKS * 256) {
            float4 p = p4[i];
            float4 t = t4[i];
            float s;
            s = __fdividef(1.f, 1.f + __expf(-p.x)); inter = fmaf(s, t.x, inter); uni += s + t.x;
            s = __fdividef(1.f, 1.f + __expf(-p.y)); inter = fmaf(s, t.y, inter); uni += s + t.y;
            s = __fdividef(1.f, 1.f + __expf(-p.z)); inter = fmaf(s, t.z, inter); uni += s + t.z;
            s = __fdividef(1.f, 1.f + __expf(-p.w)); inter = fmaf(s, t.w, inter); uni += s + t.w;
        }
        float bi = block_sum256(inter);
        float bu = block_sum256(uni);
        if (threadIdx.x == 0) { inter_p[bid] = bi; uni_p[bid] = bu; }
        return;
    }

    // ---- chamfer partials ----
    int cb      = bid - DICE_BLOCKS;
    int per_dir = gxp * chm;
    int dir     = cb / per_dir;
    int rem     = cb - dir * per_dir;
    int cy      = rem / gxp;          // target chunk
    int cx      = rem - cy * gxp;     // query-point group
    const float2* A = dir ? T : P;
    const float2* B = dir ? P : T;
    int nA = dir ? M : N;
    int nB = dir ? N : M;

    int tb = cy * TCH;
    if (tb >= nB) return;             // uniform per block

    __shared__ float4 bs[TCH];
    int t = threadIdx.x;
    if (t < TCH) {
        float bx = 0.f, by = 0.f, s2 = __uint_as_float(INFBITS);
        if (tb + t < nB) {
            float2 b = B[tb + t];
            bx = b.x; by = b.y;
            s2 = fmaf(bx, bx, by * by);
        }
        bs[t] = make_float4(bx, by, s2, 0.f);   // OOB pads +inf -> never wins min
    }
    __syncthreads();

    int abase = cx * (PTS * 256);
    float nx[PTS], ny[PTS], mn[PTS];
#pragma unroll
    for (int i = 0; i < PTS; ++i) {
        int p = abase + i * 256 + t;
        nx[i] = 0.f; ny[i] = 0.f;
        mn[i] = __uint_as_float(INFBITS);
        if (p < nA) {
            float2 a = A[p];
            nx[i] = -2.f * a.x;
            ny[i] = -2.f * a.y;
        }
    }

    // 1 broadcast ds_read_b128 per j feeds 48 VALU insts; 16 independent
    // min-chains give ILP; dice co-resident waves give TLP.
#pragma unroll 4
    for (int j = 0; j < TCH; ++j) {
        float4 b = bs[j];
#pragma unroll
        for (int i = 0; i < PTS; ++i)
            mn[i] = fminf(mn[i], fmaf(nx[i], b.x, fmaf(ny[i], b.y, b.z)));
    }

    float* dstc = pm + ((size_t)dir * chm + cy) * npm;
#pragma unroll
    for (int i = 0; i < PTS; ++i) {
        int p = abase + i * 256 + t;
        if (p < nA) dstc[p] = mn[i];
    }
}

// ---------- K2: fused finalize ----------
// grid = 2*gxf blocks; per-point min across chunks, + ||a||^2, block sum;
// last block combines dice partials + chamfer block sums into the scalar.
__global__ void __launch_bounds__(256) finalize_all(
        const float* __restrict__ pm, int npm, int chm,
        int N, int M, int nch0, int nch1,
        const float2* __restrict__ P, const float2* __restrict__ T,
        const float* __restrict__ inter_p, const float* __restrict__ uni_p,
        float* __restrict__ bsum, unsigned int* __restrict__ counter,
        int gxf, float* __restrict__ out) {
    int blk = blockIdx.x;
    int dir = blk / gxf;
    int bx  = blk - dir * gxf;
    int nA  = dir ? M : N;
    int nch = dir ? nch1 : nch0;
    const float2* A = dir ? T : P;

    int p = bx * 256 + threadIdx.x;
    float v = 0.f;
    if (p < nA) {
        const float* src = pm + (size_t)dir * chm * npm + p;
        float m = __uint_as_float(INFBITS);
#pragma unroll 16
        for (int c = 0; c < nch; ++c) m = fminf(m, src[(size_t)c * npm]);
        float2 a = A[p];
        v = m + fmaf(a.x, a.x, a.y * a.y);   // add the deferred ||a||^2
    }
    float s = block_sum256(v);

    __shared__ int is_last;
    if (threadIdx.x == 0) {
        bsum[blk] = s;
        __threadfence();
        unsigned int old = atomicAdd(counter, 1u);
        is_last = (old == (unsigned)(2 * gxf - 1));
    }
    __syncthreads();
    if (!is_last) return;
    __threadfence();

    float inter = 0.f, uni = 0.f, c0 = 0.f, c1 = 0.f;
    for (int i = threadIdx.x; i < DICE_BLOCKS; i += 256) {
        inter += inter_p[i];
        uni   += uni_p[i];
    }
    const volatile float* vb = bsum;
    for (int i = threadIdx.x; i < gxf; i += 256) {
        c0 += vb[i];
        c1 += vb[gxf + i];
    }
    float bi  = block_sum256(inter);
    float bu  = block_sum256(uni);
    float bc0 = block_sum256(c0);
    float bc1 = block_sum256(c1);
    if (threadIdx.x == 0) {
        const float SMOOTH = 1e-6f;
        float dice    = (2.f * bi + SMOOTH) / (bu + SMOOTH);
        float chamfer = bc0 / (float)N + bc1 / (float)M;
        out[0] = 0.5f * (1.f - dice) + 0.5f * chamfer;
    }
}

extern "C" void kernel_launch(void* const* d_in, const int* in_sizes, int n_in,
                              void* d_out, int out_size, void* d_ws, size_t ws_size,
                              hipStream_t stream) {
    const float*  pred = (const float*)d_in[0];
    const float*  targ = (const float*)d_in[1];
    const float2* pp   = (const float2*)d_in[2];
    const float2* tp   = (const float2*)d_in[3];
    int n = in_sizes[0];
    int N = in_sizes[2] / 2;
    int M = in_sizes[3] / 2;
    float* out = (float*)d_out;

    int npm  = N > M ? N : M;
    int nch0 = (M + TCH - 1) / TCH;
    int nch1 = (N + TCH - 1) / TCH;
    int chm  = nch0 > nch1 ? nch0 : nch1;
    int gxp  = (npm + PTS * 256 - 1) / (PTS * 256);
    int gxf  = (npm + 255) / 256;

    // ws layout: pm | inter_p | uni_p | bsum | counter
    char*  ws      = (char*)d_ws;
    float* pm      = (float*)ws;
    size_t pm_bytes = (size_t)2 * chm * npm * sizeof(float);
    size_t off     = (pm_bytes + 255) & ~(size_t)255;
    float* inter_p = (float*)(ws + off);
    float* uni_p   = inter_p + DICE_BLOCKS;
    float* bsum    = uni_p + DICE_BLOCKS;
    unsigned int* counter = (unsigned int*)(bsum + 2 * gxf);

    int cham_blocks = 2 * gxp * chm;
    fused_partials<<<DICE_BLOCKS + cham_blocks, 256, 0, stream>>>(
        (const float4*)pred, (const float4*)targ, n / 4,
        inter_p, uni_p, pp, tp, N, M, pm, npm, chm, gxp, counter);

    finalize_all<<<2 * gxf, 256, 0, stream>>>(pm, npm, chm, N, M, nch0, nch1,
                                              pp, tp, inter_p, uni_p, bsum,
                                              counter, gxf, out);
}

// Round 9
// 28.711 us; speedup vs baseline: 1.2703x; 1.1726x over previous
//
#include <hip/hip_runtime.h>
#include <math.h>

#define INFBITS 0x7F800000u
#define TCH 128          // target points staged per chamfer block (R6 value)
#define PTS 8            // query points per thread (R6 value)
#define DICE_BLOCKS 512

// ---------- block-wide sum (blockDim.x == 256, 4 waves) ----------
__device__ __forceinline__ float block_sum256(float v) {
#pragma unroll
    for (int o = 32; o > 0; o >>= 1) v += __shfl_down(v, o, 64);
    __shared__ float sb[4];
    if ((threadIdx.x & 63) == 0) sb[threadIdx.x >> 6] = v;
    __syncthreads();
    float r = sb[0] + sb[1] + sb[2] + sb[3];
    __syncthreads();
    return r;
}

// ---------- K1: fused dice partials + chamfer partial mins ----------
// blocks [0, DICE_BLOCKS)          : dice grid-stride partial sums
// blocks [DICE_BLOCKS, +2*gxp*chm) : chamfer partial mins
//
// R9 change vs R6 (one lever): LDS stores ONLY packed float2 xy[TCH]; the
// inner loop reads TWO points per ds_read_b128 (j-pairs) and recomputes
// ||b||^2 in VALU (2 insts/j shared across all PTS chains). LDS-pipe demand
// halves (5.1 -> 2.6 us) at +8% VALU and ZERO extra VGPRs — R8 showed the
// VGPR<=64 / 8-waves-per-SIMD constraint is binding (PTS=16 crossed it and
// lost 5 us despite identical LDS math).
// ||a||^2 stays deferred to K2 (min is invariant to per-point constants).
__global__ void __launch_bounds__(256) fused_partials(
        const float4* __restrict__ p4, const float4* __restrict__ t4, int n4,
        float* __restrict__ inter_p, float* __restrict__ uni_p,
        const float2* __restrict__ P, const float2* __restrict__ T,
        int N, int M, float* __restrict__ pm, int npm, int chm, int gxp,
        unsigned int* __restrict__ counter) {
    int bid = blockIdx.x;
    if (bid == 0 && threadIdx.x == 0) *counter = 0u;   // reset K2's semaphore

    if (bid < DICE_BLOCKS) {
        float inter = 0.f, uni = 0.f;
#pragma unroll 2
        for (int i = bid * 256 + threadIdx.x; i < n4; i += DICE_BLOCKS * 256) {
            float4 p = p4[i];
            float4 t = t4[i];
            float s;
            s = __fdividef(1.f, 1.f + __expf(-p.x)); inter = fmaf(s, t.x, inter); uni += s + t.x;
            s = __fdividef(1.f, 1.f + __expf(-p.y)); inter = fmaf(s, t.y, inter); uni += s + t.y;
            s = __fdividef(1.f, 1.f + __expf(-p.z)); inter = fmaf(s, t.z, inter); uni += s + t.z;
            s = __fdividef(1.f, 1.f + __expf(-p.w)); inter = fmaf(s, t.w, inter); uni += s + t.w;
        }
        float bi = block_sum256(inter);
        float bu = block_sum256(uni);
        if (threadIdx.x == 0) { inter_p[bid] = bi; uni_p[bid] = bu; }
        return;
    }

    // ---- chamfer partials ----
    int cb      = bid - DICE_BLOCKS;
    int per_dir = gxp * chm;
    int dir     = cb / per_dir;
    int rem     = cb - dir * per_dir;
    int cy      = rem / gxp;          // target chunk
    int cx      = rem - cy * gxp;     // query-point group
    const float2* A = dir ? T : P;
    const float2* B = dir ? P : T;
    int nA = dir ? M : N;
    int nB = dir ? N : M;

    int tb = cy * TCH;
    if (tb >= nB) return;             // uniform per block

    __shared__ __align__(16) float2 xy[TCH];
    int t = threadIdx.x;
    if (t < TCH) {
        // OOB pad: huge coords -> sb2 ~ 1e36 -> never wins the min
        float2 b = make_float2(1e18f, 1e18f);
        if (tb + t < nB) b = B[tb + t];
        xy[t] = b;
    }
    __syncthreads();

    int abase = cx * (PTS * 256);
    float nx[PTS], ny[PTS], mn[PTS];
#pragma unroll
    for (int i = 0; i < PTS; ++i) {
        int p = abase + i * 256 + t;
        nx[i] = 0.f; ny[i] = 0.f;
        mn[i] = __uint_as_float(INFBITS);
        if (p < nA) {
            float2 a = A[p];
            nx[i] = -2.f * a.x;
            ny[i] = -2.f * a.y;
        }
    }

    // one broadcast ds_read_b128 per TWO targets; ||b||^2 recomputed in VALU
    // (2 insts/j, amortized over PTS=8 chains -> 52 VALU per b128)
#pragma unroll 4
    for (int j = 0; j < TCH; j += 2) {
        float4 q = *(const float4*)&xy[j];            // {b0.x,b0.y,b1.x,b1.y}
        float s20 = fmaf(q.x, q.x, q.y * q.y);
        float s21 = fmaf(q.z, q.z, q.w * q.w);
#pragma unroll
        for (int i = 0; i < PTS; ++i)
            mn[i] = fminf(mn[i], fmaf(nx[i], q.x, fmaf(ny[i], q.y, s20)));
#pragma unroll
        for (int i = 0; i < PTS; ++i)
            mn[i] = fminf(mn[i], fmaf(nx[i], q.z, fmaf(ny[i], q.w, s21)));
    }

    float* dstc = pm + ((size_t)dir * chm + cy) * npm;
#pragma unroll
    for (int i = 0; i < PTS; ++i) {
        int p = abase + i * 256 + t;
        if (p < nA) dstc[p] = mn[i];
    }
}

// ---------- K2: fused finalize ----------
// grid = 2*gxf blocks; per-point min across chunks, + ||a||^2, block sum;
// last block combines dice partials + chamfer block sums into the scalar.
__global__ void __launch_bounds__(256) finalize_all(
        const float* __restrict__ pm, int npm, int chm,
        int N, int M, int nch0, int nch1,
        const float2* __restrict__ P, const float2* __restrict__ T,
        const float* __restrict__ inter_p, const float* __restrict__ uni_p,
        float* __restrict__ bsum, unsigned int* __restrict__ counter,
        int gxf, float* __restrict__ out) {
    int blk = blockIdx.x;
    int dir = blk / gxf;
    int bx  = blk - dir * gxf;
    int nA  = dir ? M : N;
    int nch = dir ? nch1 : nch0;
    const float2* A = dir ? T : P;

    int p = bx * 256 + threadIdx.x;
    float v = 0.f;
    if (p < nA) {
        const float* src = pm + (size_t)dir * chm * npm + p;
        float m = __uint_as_float(INFBITS);
#pragma unroll 16
        for (int c = 0; c < nch; ++c) m = fminf(m, src[(size_t)c * npm]);
        float2 a = A[p];
        v = m + fmaf(a.x, a.x, a.y * a.y);   // add the deferred ||a||^2
    }
    float s = block_sum256(v);

    __shared__ int is_last;
    if (threadIdx.x == 0) {
        bsum[blk] = s;
        __threadfence();
        unsigned int old = atomicAdd(counter, 1u);
        is_last = (old == (unsigned)(2 * gxf - 1));
    }
    __syncthreads();
    if (!is_last) return;
    __threadfence();

    float inter = 0.f, uni = 0.f, c0 = 0.f, c1 = 0.f;
    for (int i = threadIdx.x; i < DICE_BLOCKS; i += 256) {
        inter += inter_p[i];
        uni   += uni_p[i];
    }
    const volatile float* vb = bsum;
    for (int i = threadIdx.x; i < gxf; i += 256) {
        c0 += vb[i];
        c1 += vb[gxf + i];
    }
    float bi  = block_sum256(inter);
    float bu  = block_sum256(uni);
    float bc0 = block_sum256(c0);
    float bc1 = block_sum256(c1);
    if (threadIdx.x == 0) {
        const float SMOOTH = 1e-6f;
        float dice    = (2.f * bi + SMOOTH) / (bu + SMOOTH);
        float chamfer = bc0 / (float)N + bc1 / (float)M;
        out[0] = 0.5f * (1.f - dice) + 0.5f * chamfer;
    }
}

extern "C" void kernel_launch(void* const* d_in, const int* in_sizes, int n_in,
                              void* d_out, int out_size, void* d_ws, size_t ws_size,
                              hipStream_t stream) {
    const float*  pred = (const float*)d_in[0];
    const float*  targ = (const float*)d_in[1];
    const float2* pp   = (const float2*)d_in[2];
    const float2* tp   = (const float2*)d_in[3];
    int n = in_sizes[0];
    int N = in_sizes[2] / 2;
    int M = in_sizes[3] / 2;
    float* out = (float*)d_out;

    int npm  = N > M ? N : M;
    int nch0 = (M + TCH - 1) / TCH;
    int nch1 = (N + TCH - 1) / TCH;
    int chm  = nch0 > nch1 ? nch0 : nch1;
    int gxp  = (npm + PTS * 256 - 1) / (PTS * 256);
    int gxf  = (npm + 255) / 256;

    // ws layout: pm | inter_p | uni_p | bsum | counter
    char*  ws      = (char*)d_ws;
    float* pm      = (float*)ws;
    size_t pm_bytes = (size_t)2 * chm * npm * sizeof(float);
    size_t off     = (pm_bytes + 255) & ~(size_t)255;
    float* inter_p = (float*)(ws + off);
    float* uni_p   = inter_p + DICE_BLOCKS;
    float* bsum    = uni_p + DICE_BLOCKS;
    unsigned int* counter = (unsigned int*)(bsum + 2 * gxf);

    int cham_blocks = 2 * gxp * chm;
    fused_partials<<<DICE_BLOCKS + cham_blocks, 256, 0, stream>>>(
        (const float4*)pred, (const float4*)targ, n / 4,
        inter_p, uni_p, pp, tp, N, M, pm, npm, chm, gxp, counter);

    finalize_all<<<2 * gxf, 256, 0, stream>>>(pm, npm, chm, N, M, nch0, nch1,
                                              pp, tp, inter_p, uni_p, bsum,
                                              counter, gxf, out);
}